// Round 2
// baseline (324.765 us; speedup 1.0000x reference)
//
#include <hip/hip_runtime.h>

// RGCNDirectional: out = sum_r (A[r] @ (X @ W[r]^T)) / (rowsum(A[r]) + eps)
// X:[4096,128] f32, A:[8,4096,4096] f32 (512MB -> HBM-bound), W:[8,128,128] f32.
// Round 2: barrier-free, LDS-free streaming MFMA. Fragments load directly
// from global (A: f32->bf16 in regs, reg-double-buffered one K-tile ahead;
// Ht: bf16 o-major, L2-resident per XCD). Rowsum fused in-register.

#define N_NODES 4096
#define DIM     128
#define NREL    8
#define EPS_F   1e-12f
#define BM      64
#define BK      64
#define NKT     (N_NODES / BK)

typedef __attribute__((ext_vector_type(4))) float f32x4;
typedef __attribute__((ext_vector_type(8))) short bf16x8;

__device__ __forceinline__ unsigned short f2bf(float f) {
  unsigned u = __float_as_uint(f);
  unsigned r = (u + 0x7fffu + ((u >> 16) & 1u)) >> 16;   // RNE
  return (unsigned short)r;
}

__device__ __forceinline__ bf16x8 cvt8(const float* p) {
  f32x4 lo = *reinterpret_cast<const f32x4*>(p);
  f32x4 hi = *reinterpret_cast<const f32x4*>(p + 4);
  bf16x8 o;
#pragma unroll
  for (int j = 0; j < 4; ++j) { o[j] = (short)f2bf(lo[j]); o[j + 4] = (short)f2bf(hi[j]); }
  return o;
}

// ---------------------------------------------------------------------------
// Kernel 1: Ht[r][o][n] = sum_d X[n][d] * W[r][o][d], bf16, o-major.
// ---------------------------------------------------------------------------
__global__ __launch_bounds__(256) void h_kernel(const float* __restrict__ X,
                                                const float* __restrict__ W,
                                                short* __restrict__ Ht) {
  const int r  = blockIdx.x >> 5;          // 32 n-tiles of 128
  const int n0 = (blockIdx.x & 31) * 128;
  const int lane = threadIdx.x & 63;
  const int wid  = threadIdx.x >> 6;
  const int wm = wid >> 1, wn = wid & 1;   // 2x2 wave grid, 64x64 per wave
  const int l15 = lane & 15, l4 = lane >> 4;

  const float* Wr = W + (size_t)r * DIM * DIM;
  f32x4 acc[4][4] = {};

#pragma unroll
  for (int ks = 0; ks < 4; ++ks) {         // K = 128 = 4 * 32
    const int k = ks * 32 + l4 * 8;
    bf16x8 a[4], b[4];
#pragma unroll
    for (int mi = 0; mi < 4; ++mi)
      a[mi] = cvt8(Wr + (size_t)(wm * 64 + mi * 16 + l15) * DIM + k);
#pragma unroll
    for (int ni = 0; ni < 4; ++ni)
      b[ni] = cvt8(X + (size_t)(n0 + wn * 64 + ni * 16 + l15) * DIM + k);
#pragma unroll
    for (int mi = 0; mi < 4; ++mi)
#pragma unroll
      for (int ni = 0; ni < 4; ++ni)
        acc[mi][ni] = __builtin_amdgcn_mfma_f32_16x16x32_bf16(a[mi], b[ni], acc[mi][ni], 0, 0, 0);
  }

#pragma unroll
  for (int mi = 0; mi < 4; ++mi)
#pragma unroll
    for (int ni = 0; ni < 4; ++ni)
#pragma unroll
      for (int i = 0; i < 4; ++i) {
        const int o = wm * 64 + mi * 16 + l4 * 4 + i;
        const int n = n0 + wn * 64 + ni * 16 + l15;
        Ht[((size_t)r * DIM + o) * N_NODES + n] = (short)f2bf(acc[mi][ni][i]);
      }
}

// ---------------------------------------------------------------------------
// Kernel 2: main. Block = (relation r, 64 out rows); 4 waves x 16 rows each.
// No LDS, no barriers. Per K-step (BK=64): 4 A-loads (f32, HBM) + 16 H-loads
// (bf16, L2) + 16 MFMA, all register-resident. A double-buffered one tile
// ahead; H loads issued BEFORE the A prefetch so MFMAs' vmcnt waits leave the
// HBM prefetch in flight. Rowsum accumulated from f32 A values in-register.
// ---------------------------------------------------------------------------
__global__ __launch_bounds__(256, 2) void rgcn_main(const float* __restrict__ A,
                                                    const short* __restrict__ Ht,
                                                    float* __restrict__ out) {
  // XCD swizzle (512 = 8 XCD * 64): XCD x owns relation x -> Ht[r] (1MB)
  // stays resident in that XCD's L2.
  const int nwg = gridDim.x;
  const int logical = (blockIdx.x & 7) * (nwg >> 3) + (blockIdx.x >> 3);
  const int r  = logical >> 6;       // 64 m-tiles per relation
  const int m0 = (logical & 63) * BM;

  const int lane = threadIdx.x & 63;
  const int w    = threadIdx.x >> 6;       // wave owns rows m0+w*16 .. +16
  const int l15  = lane & 15, l4 = lane >> 4;

  const float* Arow = A + ((size_t)r * N_NODES + m0 + w * 16 + l15) * N_NODES + l4 * 8;
  const short* Hlane = Ht + (size_t)r * DIM * N_NODES + (size_t)l15 * N_NODES + l4 * 8;

  f32x4 acc[8] = {};          // ni = 0..7 (128 cols)
  f32x4 a0[2][2], a1[2][2];   // [ks][lo/hi]: 8 f32 at k = ks*32 + l4*8
  bf16x8 h[2][8];             // [ks][ni]
  float rs = 0.f;

  auto loadA = [&](f32x4 (&dst)[2][2], int kt) {
    const float* p = Arow + kt * BK;
#pragma unroll
    for (int ks = 0; ks < 2; ++ks) {
      dst[ks][0] = *reinterpret_cast<const f32x4*>(p + ks * 32);
      dst[ks][1] = *reinterpret_cast<const f32x4*>(p + ks * 32 + 4);
    }
  };
  auto loadH = [&](int kt) {
#pragma unroll
    for (int ks = 0; ks < 2; ++ks)
#pragma unroll
      for (int ni = 0; ni < 8; ++ni)
        h[ks][ni] = *reinterpret_cast<const bf16x8*>(Hlane + (size_t)ni * 16 * N_NODES + kt * BK + ks * 32);
  };
  auto compute = [&](f32x4 (&as)[2][2]) {
#pragma unroll
    for (int ks = 0; ks < 2; ++ks) {
      bf16x8 ab;
#pragma unroll
      for (int j = 0; j < 4; ++j) {
        ab[j]     = (short)f2bf(as[ks][0][j]);
        ab[j + 4] = (short)f2bf(as[ks][1][j]);
        rs += as[ks][0][j] + as[ks][1][j];
      }
#pragma unroll
      for (int ni = 0; ni < 8; ++ni)
        acc[ni] = __builtin_amdgcn_mfma_f32_16x16x32_bf16(ab, h[ks][ni], acc[ni], 0, 0, 0);
    }
  };

  loadA(a0, 0);
  for (int kt = 0; kt < NKT; kt += 2) {
    loadH(kt);
    loadA(a1, kt + 1);        // HBM prefetch AFTER H loads: MFMAs wait only on H
    compute(a0);
    loadH(kt + 1);
    if (kt + 2 < NKT) loadA(a0, kt + 2);
    compute(a1);
  }

  // rowsum reduce across l4 groups (lanes l15, l15+16, l15+32, l15+48)
  rs += __shfl_xor(rs, 16);
  rs += __shfl_xor(rs, 32);
  float ninv[4];
#pragma unroll
  for (int i = 0; i < 4; ++i)
    ninv[i] = 1.0f / (__shfl(rs, l4 * 4 + i) + EPS_F);   // lane idx has l15 == row

  float* orow = out + (size_t)(m0 + w * 16) * DIM;
#pragma unroll
  for (int ni = 0; ni < 8; ++ni)
#pragma unroll
    for (int i = 0; i < 4; ++i)
      atomicAdd(&orow[(size_t)(l4 * 4 + i) * DIM + ni * 16 + l15], acc[ni][i] * ninv[i]);
}

extern "C" void kernel_launch(void* const* d_in, const int* in_sizes, int n_in,
                              void* d_out, int out_size, void* d_ws, size_t ws_size,
                              hipStream_t stream) {
  const float* X = (const float*)d_in[0];
  const float* A = (const float*)d_in[1];
  const float* W = (const float*)d_in[2];
  float* out = (float*)d_out;
  short* Ht = (short*)d_ws;   // 8 * 128 * 4096 bf16 = 8 MB

  hipMemsetAsync(d_out, 0, (size_t)out_size * sizeof(float), stream);
  hipLaunchKernelGGL(h_kernel, dim3(NREL * (N_NODES / 128)), dim3(256), 0, stream, X, W, Ht);
  hipLaunchKernelGGL(rgcn_main, dim3(NREL * (N_NODES / BM)), dim3(256), 0, stream, A, Ht, out);
}

// Round 3
// 157.879 us; speedup vs baseline: 2.0571x; 2.0571x over previous
//
#include <hip/hip_runtime.h>

// RGCNDirectional: out = sum_r (A[r] @ (X @ W[r]^T)) / (rowsum(A[r]) + eps)
// X:[4096,128] f32, A:[8,4096,4096] f32 (512MB -> HBM-bound), W:[8,128,128] f32.
// Round 3: H staged to LDS via global_load_lds from a pre-swizzled tile layout
// (shared by all 4 waves); A direct-to-reg double-buffered; counted
// s_waitcnt vmcnt(8) + raw s_barrier so prefetch stays in flight across the
// barrier (no per-iter drain). Rowsum of f32 A fused in-register.

#define N_NODES 4096
#define DIM     128
#define NREL    8
#define EPS_F   1e-12f
#define BM      64
#define BK      64
#define NKT     (N_NODES / BK)   // 64
#define TILE_SHORTS (DIM * BK)   // 8192 shorts = 16 KB per H tile

typedef __attribute__((ext_vector_type(4))) float f32x4;
typedef __attribute__((ext_vector_type(8))) short bf16x8;

__device__ __forceinline__ unsigned short f2bf(float f) {
  unsigned u = __float_as_uint(f);
  return (unsigned short)((u + 0x7fffu + ((u >> 16) & 1u)) >> 16);   // RNE
}

__device__ __forceinline__ bf16x8 cvt8(const float* p) {
  f32x4 lo = *reinterpret_cast<const f32x4*>(p);
  f32x4 hi = *reinterpret_cast<const f32x4*>(p + 4);
  bf16x8 o;
#pragma unroll
  for (int j = 0; j < 4; ++j) { o[j] = (short)f2bf(lo[j]); o[j + 4] = (short)f2bf(hi[j]); }
  return o;
}

__device__ __forceinline__ void gload_lds16(const void* g, void* l) {
  __builtin_amdgcn_global_load_lds((const __attribute__((address_space(1))) void*)g,
                                   (__attribute__((address_space(3))) void*)l, 16, 0, 0);
}

// ---------------------------------------------------------------------------
// Kernel 1: Ht2[r][kt][ o*64 + (c ^ ((o&7)<<3)) ] = bf16( sum_d X[n][d]*W[r][o][d] )
// where n = kt*64 + c. Tile-contiguous + XOR-swizzled so the main kernel's
// global_load_lds staging is linear and its ds_read_b128 is conflict-free.
// ---------------------------------------------------------------------------
__global__ __launch_bounds__(256) void h_kernel(const float* __restrict__ X,
                                                const float* __restrict__ W,
                                                short* __restrict__ Ht2) {
  const int r  = blockIdx.x >> 5;          // 32 n-tiles of 128
  const int n0 = (blockIdx.x & 31) * 128;
  const int lane = threadIdx.x & 63;
  const int wid  = threadIdx.x >> 6;
  const int wm = wid >> 1, wn = wid & 1;   // 2x2 wave grid, 64x64 per wave
  const int l15 = lane & 15, l4 = lane >> 4;

  const float* Wr = W + (size_t)r * DIM * DIM;
  f32x4 acc[4][4] = {};

#pragma unroll
  for (int ks = 0; ks < 4; ++ks) {         // K = 128 = 4 * 32
    const int k = ks * 32 + l4 * 8;
    bf16x8 a[4], b[4];
#pragma unroll
    for (int mi = 0; mi < 4; ++mi)
      a[mi] = cvt8(Wr + (size_t)(wm * 64 + mi * 16 + l15) * DIM + k);
#pragma unroll
    for (int ni = 0; ni < 4; ++ni)
      b[ni] = cvt8(X + (size_t)(n0 + wn * 64 + ni * 16 + l15) * DIM + k);
#pragma unroll
    for (int mi = 0; mi < 4; ++mi)
#pragma unroll
      for (int ni = 0; ni < 4; ++ni)
        acc[mi][ni] = __builtin_amdgcn_mfma_f32_16x16x32_bf16(a[mi], b[ni], acc[mi][ni], 0, 0, 0);
  }

#pragma unroll
  for (int mi = 0; mi < 4; ++mi)
#pragma unroll
    for (int ni = 0; ni < 4; ++ni)
#pragma unroll
      for (int i = 0; i < 4; ++i) {
        const int o = wm * 64 + mi * 16 + l4 * 4 + i;
        const int n = n0 + wn * 64 + ni * 16 + l15;
        const int kt = n >> 6, c = n & 63;
        Ht2[(size_t)(r * NKT + kt) * TILE_SHORTS + o * 64 + (c ^ ((o & 7) << 3))] =
            (short)f2bf(acc[mi][ni][i]);
      }
}

// ---------------------------------------------------------------------------
// Kernel 2: main. Block = (relation r, 64 out rows); wave w owns rows w*16..+16.
// Per K-tile: stage next H tile (4x global_load_lds/wave), 4x A dwordx4 loads
// (next tile, regs), counted vmcnt(8) + raw barrier (prefetch survives), then
// 16 MFMA from LDS-H (swizzled ds_read_b128) and reg-A (cvt to bf16 inline).
// ---------------------------------------------------------------------------
__global__ __launch_bounds__(256, 2) void rgcn_main(const float* __restrict__ A,
                                                    const short* __restrict__ Ht2,
                                                    float* __restrict__ out) {
  // XCD swizzle (512 = 8 XCD * 64): XCD x owns relation x -> Ht2[r] (1MB)
  // stays resident in that XCD's L2.
  const int nwg = gridDim.x;
  const int logical = (blockIdx.x & 7) * (nwg >> 3) + (blockIdx.x >> 3);
  const int r  = logical >> 6;
  const int m0 = (logical & 63) * BM;

  const int lane = threadIdx.x & 63;
  const int w    = threadIdx.x >> 6;
  const int l15  = lane & 15, l4 = lane >> 4;

  __shared__ __align__(128) short Hs[2][TILE_SHORTS];   // 32 KB

  const float* Arow = A + ((size_t)r * N_NODES + m0 + w * 16 + l15) * N_NODES + l4 * 8;
  const short* Hg   = Ht2 + (size_t)r * NKT * TILE_SHORTS + w * 4 * 512 + lane * 8;
  short* lds0 = &Hs[0][0] + w * 2048;   // wave-uniform staging base (4 KB/wave)
  short* lds1 = &Hs[1][0] + w * 2048;

  f32x4 acc[8] = {};
  f32x4 a0[2][2], a1[2][2];   // [ks][lo/hi]: 8 f32 at k = ks*32 + l4*8
  float rs = 0.f;

  auto stage = [&](short* ldsb, int kt) {
    const short* g = Hg + (size_t)kt * TILE_SHORTS;
#pragma unroll
    for (int j = 0; j < 4; ++j)
      gload_lds16(g + j * 512, ldsb + j * 512);
  };
  auto loadA = [&](f32x4 (&d)[2][2], int kt) {
    const float* p = Arow + kt * BK;
    d[0][0] = *reinterpret_cast<const f32x4*>(p);
    d[0][1] = *reinterpret_cast<const f32x4*>(p + 4);
    d[1][0] = *reinterpret_cast<const f32x4*>(p + 32);
    d[1][1] = *reinterpret_cast<const f32x4*>(p + 36);
  };

  const char* hbase = (const char*)&Hs[0][0] + (size_t)l15 * 128;
  const int swz = (l15 & 7) << 4;
  auto compute = [&](int buf, f32x4 (&av)[2][2]) {
    const char* hb = hbase + buf * (TILE_SHORTS * 2);
#pragma unroll
    for (int ks = 0; ks < 2; ++ks) {
      bf16x8 ab;
#pragma unroll
      for (int j = 0; j < 4; ++j) {
        ab[j]     = (short)f2bf(av[ks][0][j]);
        ab[j + 4] = (short)f2bf(av[ks][1][j]);
        rs += av[ks][0][j] + av[ks][1][j];
      }
      const int cb = ks * 64 + l4 * 16;
#pragma unroll
      for (int ni = 0; ni < 8; ++ni) {
        bf16x8 h = *reinterpret_cast<const bf16x8*>(hb + ni * 2048 + (cb ^ swz));
        acc[ni] = __builtin_amdgcn_mfma_f32_16x16x32_bf16(ab, h, acc[ni], 0, 0, 0);
      }
    }
  };

  // prologue: fill tile 0, full drain once
  stage(lds0, 0);
  loadA(a0, 0);
  __builtin_amdgcn_sched_barrier(0);
  asm volatile("s_waitcnt vmcnt(0)" ::: "memory");
  __builtin_amdgcn_sched_barrier(0);
  __builtin_amdgcn_s_barrier();

  for (int t = 0; t < NKT; t += 2) {
    {
      const int nt = (t + 1 < NKT) ? (t + 1) : (NKT - 1);
      stage(lds1, nt);
      loadA(a1, nt);
      __builtin_amdgcn_sched_barrier(0);
      asm volatile("s_waitcnt vmcnt(8)" ::: "memory");  // keep newest 8 in flight
      __builtin_amdgcn_sched_barrier(0);
      __builtin_amdgcn_s_barrier();                     // H(t) visible to all
      compute(0, a0);
      __builtin_amdgcn_sched_barrier(0);
      __builtin_amdgcn_s_barrier();                     // release buf0
    }
    {
      const int nt = (t + 2 < NKT) ? (t + 2) : (NKT - 1);
      stage(lds0, nt);
      loadA(a0, nt);
      __builtin_amdgcn_sched_barrier(0);
      asm volatile("s_waitcnt vmcnt(8)" ::: "memory");
      __builtin_amdgcn_sched_barrier(0);
      __builtin_amdgcn_s_barrier();
      compute(1, a1);
      __builtin_amdgcn_sched_barrier(0);
      __builtin_amdgcn_s_barrier();
    }
  }

  // rowsum reduce: lanes {l15, l15+16, l15+32, l15+48} hold partials of row l15
  rs += __shfl_xor(rs, 16);
  rs += __shfl_xor(rs, 32);
  float ninv[4];
#pragma unroll
  for (int i = 0; i < 4; ++i)
    ninv[i] = 1.0f / (__shfl(rs, l4 * 4 + i) + EPS_F);  // source lane's l15 == row

  float* orow = out + (size_t)(m0 + w * 16) * DIM;
#pragma unroll
  for (int ni = 0; ni < 8; ++ni)
#pragma unroll
    for (int i = 0; i < 4; ++i)
      atomicAdd(&orow[(size_t)(l4 * 4 + i) * DIM + ni * 16 + l15], acc[ni][i] * ninv[i]);
}

extern "C" void kernel_launch(void* const* d_in, const int* in_sizes, int n_in,
                              void* d_out, int out_size, void* d_ws, size_t ws_size,
                              hipStream_t stream) {
  const float* X = (const float*)d_in[0];
  const float* A = (const float*)d_in[1];
  const float* W = (const float*)d_in[2];
  float* out = (float*)d_out;
  short* Ht2 = (short*)d_ws;   // 8 r * 64 kt * 16 KB = 8 MB

  hipMemsetAsync(d_out, 0, (size_t)out_size * sizeof(float), stream);
  hipLaunchKernelGGL(h_kernel, dim3(NREL * (N_NODES / 128)), dim3(256), 0, stream, X, W, Ht2);
  hipLaunchKernelGGL(rgcn_main, dim3(NREL * (N_NODES / BM)), dim3(256), 0, stream, A, Ht2, out);
}